// Round 8
// baseline (18179.907 us; speedup 1.0000x reference)
//
#include <hip/hip_runtime.h>
#include <stdint.h>

// ---------------------------------------------------------------------------
// 2-layer LSTM (T=512, B=256, IN=64, H=1024) + Linear(H->1) + sigmoid.
// Persistent kernel, 256 blocks (1/CU), layers pipelined: phase p =
// layer1(p) + layer2(p-1), ONE group barrier per phase.
// Round-8: 512 threads / 8 waves (2 waves/SIMD) -- round-7 showed pure
// latency-exposure (MfmaUtil 8.9%, VALUBusy 10%, HBM 1%, occupancy 12% =
// 1 wave/SIMD): double TLP so remote-L2 load latency and waitcnt stalls
// overlap across co-resident waves.
//  * W2: K-split 8-way, w2r[8][4] = 128 VGPR/wave (was 256). W1: LDS 139KB.
//    C1/C2 in regs. Fences can't evict regs/LDS (round-7: FETCH 27x lower).
//  * GEMM1: row-split 4 x K-half 2, one 16KB BUF reduce, epilogue on k2=0.
//  * GEMM2: 8-way K partials -> fold waves 4-7 into 0-3 (4 tiles) ->
//    balanced 3-round all-to-all among waves 0-3 -> epilogue2.
//  * m-group = XCD pair, leaf/root tree barrier (unchanged from round 7).
// ---------------------------------------------------------------------------

#define TT   512
#define BAT  256
#define INP  64
#define HID  1024
#define KA   1088
#define KB   2048
#define SZH  (BAT*HID)
#define NBLK 256
#define NTHR 512

typedef __attribute__((ext_vector_type(8))) short bf16x8;
typedef __attribute__((ext_vector_type(4))) float f32x4;

// workspace byte offsets (256-aligned)
#define OFF_BA   0ull          // bf16 [4096][1088] packed W layer1
#define OFF_BB   8912896ull    // bf16 [4096][2048] packed W layer2
#define OFF_XB   25690112ull   // bf16 x [512][256][64]
#define OFF_H1   42467328ull   // bf16 h1 [2][256][1024]
#define OFF_H2   43515904ull   // bf16 h2 [2][256][1024]
#define OFF_Y    44564480ull   // f32 yacc [512][256][8]
#define OFF_B1P  48758784ull   // f32 packed bias layer1 [4096]
#define OFF_B2P  48775168ull   // f32 packed bias layer2 [4096]
#define OFF_BAR  48791552ull   // u32 barriers: 4 groups x 16 lines x 128B
#define WS_END   48799744ull

__device__ __forceinline__ unsigned short f2bf(float f) {
  unsigned u = __float_as_uint(f);
  u += 0x7FFFu + ((u >> 16) & 1u);
  return (unsigned short)(u >> 16);
}
__device__ __forceinline__ float sigm_(float x) { return 1.0f / (1.0f + __expf(-x)); }
__device__ __forceinline__ float tanh_(float x) {
  float t = __expf(-2.0f * fabsf(x));
  float r = (1.0f - t) / (1.0f + t);
  return x < 0.0f ? -r : r;
}
__device__ __forceinline__ f32x4 mfma16(bf16x8 a, bf16x8 b, f32x4 c) {
  return __builtin_amdgcn_mfma_f32_16x16x32_bf16(a, b, c, 0, 0, 0);
}

// 64-block group barrier. 8 leaves (8 arrivals each) + root. Monotonic
// counters zeroed once per launch; phase is 1-based. (unchanged, proven)
__device__ __forceinline__ void group_barrier(unsigned* bar, unsigned phase, int m, int leaf) {
  __syncthreads();
  if (threadIdx.x == 0) {
    __builtin_amdgcn_fence(__ATOMIC_RELEASE, "agent");
    unsigned* lp = bar + (m * 16 + leaf) * 32;
    unsigned* rp = bar + (m * 16 + 8) * 32;
    unsigned old = __hip_atomic_fetch_add(lp, 1u, __ATOMIC_RELAXED, __HIP_MEMORY_SCOPE_AGENT);
    if (old + 1u == phase * 8u)
      __hip_atomic_fetch_add(rp, 1u, __ATOMIC_RELAXED, __HIP_MEMORY_SCOPE_AGENT);
    unsigned tgt = phase * 8u;
    int spins = 0;
    while (__hip_atomic_load(rp, __ATOMIC_RELAXED, __HIP_MEMORY_SCOPE_AGENT) < tgt) {
      __builtin_amdgcn_s_sleep(2);
      if (++spins > (1 << 17)) break;   // bail -> wrong answer, never hang
    }
    __builtin_amdgcn_fence(__ATOMIC_ACQUIRE, "agent");
  }
  __syncthreads();
}

// ---------------- prep kernels ----------------
__global__ void k_zero(unsigned* __restrict__ p, long n) {
  long i = (long)blockIdx.x * blockDim.x + threadIdx.x;
  long s = (long)gridDim.x * blockDim.x;
  for (; i < n; i += s) p[i] = 0u;
}

// pack W as B[col][k], col = bh*64 + gate*16 + h  -> wrow = gate*HID + bh*16 + h
__global__ void k_packw(const float* __restrict__ Wih, const float* __restrict__ Whh,
                        unsigned short* __restrict__ out, int kih, int K) {
  int i = blockIdx.x * blockDim.x + threadIdx.x;
  int n = 4096 * K;
  int stride = gridDim.x * blockDim.x;
  for (; i < n; i += stride) {
    int p = i / K, k = i - p * K;
    int bh = p >> 6, g = (p >> 4) & 3, h = p & 15;
    int wrow = g * HID + bh * 16 + h;
    float v = (k < kih) ? Wih[(size_t)wrow * kih + k] : Whh[(size_t)wrow * HID + (k - kih)];
    out[i] = f2bf(v);
  }
}

__global__ void k_convx(const float* __restrict__ x, unsigned short* __restrict__ xb) {
  int i = blockIdx.x * blockDim.x + threadIdx.x;
  int stride = gridDim.x * blockDim.x;
  for (; i < TT * BAT * INP; i += stride) xb[i] = f2bf(x[i]);
}

__global__ void k_bias(const float* __restrict__ bih1, const float* __restrict__ bhh1,
                       const float* __restrict__ bih2, const float* __restrict__ bhh2,
                       float* __restrict__ b1p, float* __restrict__ b2p) {
  int p = blockIdx.x * blockDim.x + threadIdx.x;
  if (p < 4096) {
    int bh = p >> 6, g = (p >> 4) & 3, h = p & 15;
    int wrow = g * HID + bh * 16 + h;
    b1p[p] = bih1[wrow] + bhh1[wrow];
    b2p[p] = bih2[wrow] + bhh2[wrow];
  }
}

// ---------------- main persistent kernel ----------------
// bid -> m = (bid&7)>>1 (64-row tile, XCD pair), bh = (bid>>3)|((bid&1)<<5).
// 8 waves: GEMM1 wave w = (r4=w&3 rows 16r4..+15, k2=w>>2 K-half of 34 chunks).
// GEMM2 wave w = K-chunks [8w, 8w+8) of 64; fold + all-to-all -> wave r owns
// row-tile r for both epilogues.
__global__ __launch_bounds__(NTHR, 2) void k_lstm(
    const unsigned short* __restrict__ BA, const unsigned short* __restrict__ BB,
    const unsigned short* __restrict__ XB,
    unsigned short* __restrict__ H1, unsigned short* __restrict__ H2,
    const float* __restrict__ B1P, const float* __restrict__ B2P,
    const float* __restrict__ W2, float* __restrict__ YACC,
    unsigned* __restrict__ BAR)
{
  __shared__ bf16x8 W1L[34 * 4 * 4 * 16];   // 139264 B: W1 frags [c][kq][g][l15]
  __shared__ f32x4  BUF[4 * 4 * 4 * 16];    //  16384 B: reduce buffer

  const int bid = blockIdx.x;
  const int s = bid & 1;
  const int m = (bid & 7) >> 1;
  const int bh = (bid >> 3) | (s << 5);
  const int leaf = s * 4 + ((bid >> 3) & 3);
  const int tid = threadIdx.x;
  const int lane = tid & 63, wave = tid >> 6;   // 0..7
  const int l15 = lane & 15, kq = lane >> 4;
  const int r4 = wave & 3, k2 = wave >> 2;
  const int grow0 = m * 64 + r4 * 16;           // row-tile this wave touches
  const int arow = grow0 + l15;                 // A-fragment row
  const int hcol = bh * 16 + l15;
  const int colb = bh * 64;

  // ---- one-time init ----
  // W1 -> LDS, flat: i = c*256 + kq*64 + g*16 + l  (17 iters per thread)
  for (int i = tid; i < 34 * 256; i += NTHR) {
    const int c = i >> 8, kqq = (i >> 6) & 3, g = (i >> 4) & 3, l = i & 15;
    W1L[i] = ((const bf16x8*)(BA + (size_t)(colb + g * 16 + l) * KA))[c * 4 + kqq];
  }
  // W2 K-slice -> VGPRs: wave w holds global 32k-chunks [8w, 8w+8)
  bf16x8 w2r[8][4];
#pragma unroll
  for (int g = 0; g < 4; ++g) {
    const bf16x8* src = (const bf16x8*)(BB + (size_t)(colb + g * 16 + l15) * KB);
#pragma unroll
    for (int cc = 0; cc < 8; ++cc) w2r[cc][g] = src[(wave * 8 + cc) * 4 + kq];
  }
  const float ba0 = B1P[colb + l15], ba1 = B1P[colb + 16 + l15],
              ba2 = B1P[colb + 32 + l15], ba3 = B1P[colb + 48 + l15];
  const float bb0 = B2P[colb + l15], bb1 = B2P[colb + 16 + l15],
              bb2 = B2P[colb + 32 + l15], bb3 = B2P[colb + 48 + l15];
  const float w2v = W2[hcol];
  float c1r[4] = {0.f, 0.f, 0.f, 0.f};   // live on waves 0-3 only
  float c2r[4] = {0.f, 0.f, 0.f, 0.f};
  __syncthreads();

  for (int p = 0; p <= TT; ++p) {
    const int cur = p & 1, prv = cur ^ 1;

    // ======== GEMM1: rows 16*r4..+15, K-half k2 (17 of 34 chunks) ========
    if (p < TT) {
      f32x4 acc1[4];
#pragma unroll
      for (int g = 0; g < 4; ++g) acc1[g] = (f32x4){0.f, 0.f, 0.f, 0.f};
      const bf16x8* xf  = (const bf16x8*)XB + ((size_t)p * BAT + arow) * 8;
      const bf16x8* h1f = (const bf16x8*)(H1 + (size_t)prv * SZH) + (size_t)arow * 128;
      const int cbeg = k2 * 17;
#pragma unroll
      for (int ci = 0; ci < 17; ++ci) {
        const int c = cbeg + ci;
        bf16x8 a = (c < 2) ? xf[c * 4 + kq] : h1f[(c - 2) * 4 + kq];
#pragma unroll
        for (int g = 0; g < 4; ++g)
          acc1[g] = mfma16(a, W1L[((c * 4 + kq) * 4 + g) * 16 + l15], acc1[g]);
      }
      // K-half reduce: k2=1 publishes, k2=0 folds + epilogue1
      if (k2 == 1) {
#pragma unroll
        for (int g = 0; g < 4; ++g)
          BUF[((r4 * 4 + g) * 4 + kq) * 16 + l15] = acc1[g];
      }
      __syncthreads();
      if (k2 == 0) {
#pragma unroll
        for (int g = 0; g < 4; ++g)
          acc1[g] += BUF[((r4 * 4 + g) * 4 + kq) * 16 + l15];
        unsigned short* h1w = H1 + (size_t)cur * SZH;
#pragma unroll
        for (int j = 0; j < 4; ++j) {
          float gi = acc1[0][j] + ba0, gf = acc1[1][j] + ba1,
                gg = acc1[2][j] + ba2, go = acc1[3][j] + ba3;
          float cn = sigm_(gf) * c1r[j] + sigm_(gi) * tanh_(gg);
          float hn = sigm_(go) * tanh_(cn);
          c1r[j] = cn;
          h1w[(size_t)(grow0 + kq * 4 + j) * HID + hcol] = f2bf(hn);
        }
      }
      __syncthreads();   // BUF reuse by GEMM2 reduce
    }

    // ======== GEMM2: K-split 8-way, full 64x64 partial per wave ========
    if (p >= 1) {
      f32x4 acc2[4][4];   // [row-tile][gate]
#pragma unroll
      for (int i = 0; i < 4; ++i)
#pragma unroll
        for (int g = 0; g < 4; ++g) acc2[i][g] = (f32x4){0.f, 0.f, 0.f, 0.f};
      const bf16x8* af = (wave < 4) ? (const bf16x8*)(H1 + (size_t)prv * SZH)
                                    : (const bf16x8*)(H2 + (size_t)cur * SZH);
      const int fo = (wave < 4 ? wave : wave - 4) * 32;   // frag offset of K-slice
#pragma unroll
      for (int cc = 0; cc < 8; ++cc) {
        bf16x8 afr[4];
#pragma unroll
        for (int i = 0; i < 4; ++i)
          afr[i] = af[(size_t)(m * 64 + i * 16 + l15) * 128 + fo + cc * 4 + kq];
#pragma unroll
        for (int i = 0; i < 4; ++i)
#pragma unroll
          for (int g = 0; g < 4; ++g) acc2[i][g] = mfma16(afr[i], w2r[cc][g], acc2[i][g]);
      }

      // stage A: fold waves 4-7 into 0-3, tile by tile (BUF = 16KB)
#pragma unroll
      for (int t = 0; t < 4; ++t) {
        if (wave >= 4) {
#pragma unroll
          for (int g = 0; g < 4; ++g)
            BUF[(((wave - 4) * 4 + g) * 4 + kq) * 16 + l15] = acc2[t][g];
        }
        __syncthreads();
        if (wave < 4) {
#pragma unroll
          for (int g = 0; g < 4; ++g)
            acc2[t][g] += BUF[((wave * 4 + g) * 4 + kq) * 16 + l15];
        }
        __syncthreads();
      }

      // stage B: balanced all-to-all among waves 0-3 (wave t ends owning tile t)
#pragma unroll
      for (int d = 1; d < 4; ++d) {
#pragma unroll
        for (int t = 0; t < 4; ++t) {
          if (wave < 4 && ((wave + d) & 3) == t) {
#pragma unroll
            for (int g = 0; g < 4; ++g)
              BUF[((wave * 4 + g) * 4 + kq) * 16 + l15] = acc2[t][g];
          }
        }
        __syncthreads();
#pragma unroll
        for (int t = 0; t < 4; ++t) {
          if (wave == t) {
            const int rs = (t - d) & 3;
#pragma unroll
            for (int g = 0; g < 4; ++g)
              acc2[t][g] += BUF[((rs * 4 + g) * 4 + kq) * 16 + l15];
          }
        }
        if (d < 3) __syncthreads();
      }

      // epilogue 2 on waves 0-3 (static extraction)
      if (wave < 4) {
        unsigned short* h2w = H2 + (size_t)prv * SZH;   // h2(p-1) -> buffer (p-1)&1
        f32x4 g0, g1, g2, g3;
#pragma unroll
        for (int t = 0; t < 4; ++t)
          if (wave == t) { g0 = acc2[t][0]; g1 = acc2[t][1]; g2 = acc2[t][2]; g3 = acc2[t][3]; }
#pragma unroll
        for (int j = 0; j < 4; ++j) {
          float gi = g0[j] + bb0, gf = g1[j] + bb1, gg = g2[j] + bb2, go = g3[j] + bb3;
          float cn = sigm_(gf) * c2r[j] + sigm_(gi) * tanh_(gg);
          float hn = sigm_(go) * tanh_(cn);
          c2r[j] = cn;
          int gr = grow0 + kq * 4 + j;
          h2w[(size_t)gr * HID + hcol] = f2bf(hn);
          float v = hn * w2v;
          v += __shfl_xor(v, 1);
          v += __shfl_xor(v, 2);
          v += __shfl_xor(v, 4);
          v += __shfl_xor(v, 8);
          if (l15 == 0) atomicAdd(YACC + ((size_t)(p - 1) * BAT + gr) * 8 + ((bid >> 3) & 7), v);
        }
      }
    }

    if (p < TT) group_barrier(BAR, (unsigned)(p + 1), m, leaf);
  }
}

__global__ void k_fin(const float* __restrict__ yacc, const float* __restrict__ b2,
                      float* __restrict__ out) {
  int i = blockIdx.x * blockDim.x + threadIdx.x;
  if (i < TT * BAT) {
    const float* y = yacc + (size_t)i * 8;
    float a = (y[0] + y[1]) + (y[2] + y[3]) + ((y[4] + y[5]) + (y[6] + y[7]));
    out[i] = 1.0f / (1.0f + __expf(-(a + b2[0])));
  }
}

// ---------------------------------------------------------------------------
extern "C" void kernel_launch(void* const* d_in, const int* in_sizes, int n_in,
                              void* d_out, int out_size, void* d_ws, size_t ws_size,
                              hipStream_t stream) {
  const float* x    = (const float*)d_in[0];
  const float* Wih1 = (const float*)d_in[1];
  const float* Whh1 = (const float*)d_in[2];
  const float* bih1 = (const float*)d_in[3];
  const float* bhh1 = (const float*)d_in[4];
  const float* Wih2 = (const float*)d_in[5];
  const float* Whh2 = (const float*)d_in[6];
  const float* bih2 = (const float*)d_in[7];
  const float* bhh2 = (const float*)d_in[8];
  const float* W2   = (const float*)d_in[9];
  const float* b2   = (const float*)d_in[10];
  (void)in_sizes; (void)n_in; (void)out_size; (void)ws_size;

  char* ws = (char*)d_ws;
  unsigned short* BA  = (unsigned short*)(ws + OFF_BA);
  unsigned short* BBp = (unsigned short*)(ws + OFF_BB);
  unsigned short* XBp = (unsigned short*)(ws + OFF_XB);
  unsigned short* H1  = (unsigned short*)(ws + OFF_H1);
  unsigned short* H2  = (unsigned short*)(ws + OFF_H2);
  float* YACC = (float*)(ws + OFF_Y);
  float* B1P  = (float*)(ws + OFF_B1P);
  float* B2P  = (float*)(ws + OFF_B2P);
  unsigned* BAR = (unsigned*)(ws + OFF_BAR);

  k_zero<<<512, 256, 0, stream>>>((unsigned*)(ws + OFF_H1), (long)((WS_END - OFF_H1) / 4));
  k_packw<<<1024, 256, 0, stream>>>(Wih1, Whh1, BA, INP, KA);
  k_packw<<<2048, 256, 0, stream>>>(Wih2, Whh2, BBp, HID, KB);
  k_convx<<<1024, 256, 0, stream>>>(x, XBp);
  k_bias<<<16, 256, 0, stream>>>(bih1, bhh1, bih2, bhh2, B1P, B2P);
  k_lstm<<<NBLK, NTHR, 0, stream>>>(BA, BBp, XBp, H1, H2, B1P, B2P, W2, YACC, BAR);
  k_fin<<<512, 256, 0, stream>>>(YACC, b2, (float*)d_out);
}

// Round 9
// 18020.589 us; speedup vs baseline: 1.0088x; 1.0088x over previous
//
#include <hip/hip_runtime.h>
#include <stdint.h>

// ---------------------------------------------------------------------------
// 2-layer LSTM (T=512, B=256, IN=64, H=1024) + Linear(H->1) + sigmoid.
// Persistent kernel, 256 blocks (1/CU), layers pipelined: phase p =
// layer1(p) + layer2(p-1), ONE group barrier per phase.
// Round-9: round-8 structure with __launch_bounds__(512, 1).
// Round-8 failure diagnosed: launch_bounds 2nd arg = min BLOCKS/CU (CUDA
// semantics); (512,2) -> 4 waves/SIMD -> 128-VGPR cap -> w2r spilled to
// scratch (FETCH 31x, VGPR_Count=128). (512,1) -> 2 waves/SIMD -> 256 cap;
// working set ~240 fits. Keeps 2x TLP vs round 7 (which was pure
// latency-exposure bound: MfmaUtil 8.9%, VALUBusy 10%, HBM 1%).
//  * W2: K-split 8-way, w2r[8][4] = 128 VGPR/wave. W1: LDS 139KB.
//    C1/C2 in regs. Fences can't evict regs/LDS (round-7: FETCH 27x lower).
//  * GEMM1: row-split 4 x K-half 2, one 16KB BUF reduce, epilogue on k2=0.
//  * GEMM2: 8-way K partials -> fold waves 4-7 into 0-3 (4 tiles) ->
//    balanced 3-round all-to-all among waves 0-3 -> epilogue2.
//  * m-group = XCD pair, leaf/root tree barrier (unchanged since round 7).
// ---------------------------------------------------------------------------

#define TT   512
#define BAT  256
#define INP  64
#define HID  1024
#define KA   1088
#define KB   2048
#define SZH  (BAT*HID)
#define NBLK 256
#define NTHR 512

typedef __attribute__((ext_vector_type(8))) short bf16x8;
typedef __attribute__((ext_vector_type(4))) float f32x4;

// workspace byte offsets (256-aligned)
#define OFF_BA   0ull          // bf16 [4096][1088] packed W layer1
#define OFF_BB   8912896ull    // bf16 [4096][2048] packed W layer2
#define OFF_XB   25690112ull   // bf16 x [512][256][64]
#define OFF_H1   42467328ull   // bf16 h1 [2][256][1024]
#define OFF_H2   43515904ull   // bf16 h2 [2][256][1024]
#define OFF_Y    44564480ull   // f32 yacc [512][256][8]
#define OFF_B1P  48758784ull   // f32 packed bias layer1 [4096]
#define OFF_B2P  48775168ull   // f32 packed bias layer2 [4096]
#define OFF_BAR  48791552ull   // u32 barriers: 4 groups x 16 lines x 128B
#define WS_END   48799744ull

__device__ __forceinline__ unsigned short f2bf(float f) {
  unsigned u = __float_as_uint(f);
  u += 0x7FFFu + ((u >> 16) & 1u);
  return (unsigned short)(u >> 16);
}
__device__ __forceinline__ float sigm_(float x) { return 1.0f / (1.0f + __expf(-x)); }
__device__ __forceinline__ float tanh_(float x) {
  float t = __expf(-2.0f * fabsf(x));
  float r = (1.0f - t) / (1.0f + t);
  return x < 0.0f ? -r : r;
}
__device__ __forceinline__ f32x4 mfma16(bf16x8 a, bf16x8 b, f32x4 c) {
  return __builtin_amdgcn_mfma_f32_16x16x32_bf16(a, b, c, 0, 0, 0);
}

// 64-block group barrier. 8 leaves (8 arrivals each) + root. Monotonic
// counters zeroed once per launch; phase is 1-based. (unchanged, proven)
__device__ __forceinline__ void group_barrier(unsigned* bar, unsigned phase, int m, int leaf) {
  __syncthreads();
  if (threadIdx.x == 0) {
    __builtin_amdgcn_fence(__ATOMIC_RELEASE, "agent");
    unsigned* lp = bar + (m * 16 + leaf) * 32;
    unsigned* rp = bar + (m * 16 + 8) * 32;
    unsigned old = __hip_atomic_fetch_add(lp, 1u, __ATOMIC_RELAXED, __HIP_MEMORY_SCOPE_AGENT);
    if (old + 1u == phase * 8u)
      __hip_atomic_fetch_add(rp, 1u, __ATOMIC_RELAXED, __HIP_MEMORY_SCOPE_AGENT);
    unsigned tgt = phase * 8u;
    int spins = 0;
    while (__hip_atomic_load(rp, __ATOMIC_RELAXED, __HIP_MEMORY_SCOPE_AGENT) < tgt) {
      __builtin_amdgcn_s_sleep(2);
      if (++spins > (1 << 17)) break;   // bail -> wrong answer, never hang
    }
    __builtin_amdgcn_fence(__ATOMIC_ACQUIRE, "agent");
  }
  __syncthreads();
}

// ---------------- prep kernels ----------------
__global__ void k_zero(unsigned* __restrict__ p, long n) {
  long i = (long)blockIdx.x * blockDim.x + threadIdx.x;
  long s = (long)gridDim.x * blockDim.x;
  for (; i < n; i += s) p[i] = 0u;
}

// pack W as B[col][k], col = bh*64 + gate*16 + h  -> wrow = gate*HID + bh*16 + h
__global__ void k_packw(const float* __restrict__ Wih, const float* __restrict__ Whh,
                        unsigned short* __restrict__ out, int kih, int K) {
  int i = blockIdx.x * blockDim.x + threadIdx.x;
  int n = 4096 * K;
  int stride = gridDim.x * blockDim.x;
  for (; i < n; i += stride) {
    int p = i / K, k = i - p * K;
    int bh = p >> 6, g = (p >> 4) & 3, h = p & 15;
    int wrow = g * HID + bh * 16 + h;
    float v = (k < kih) ? Wih[(size_t)wrow * kih + k] : Whh[(size_t)wrow * HID + (k - kih)];
    out[i] = f2bf(v);
  }
}

__global__ void k_convx(const float* __restrict__ x, unsigned short* __restrict__ xb) {
  int i = blockIdx.x * blockDim.x + threadIdx.x;
  int stride = gridDim.x * blockDim.x;
  for (; i < TT * BAT * INP; i += stride) xb[i] = f2bf(x[i]);
}

__global__ void k_bias(const float* __restrict__ bih1, const float* __restrict__ bhh1,
                       const float* __restrict__ bih2, const float* __restrict__ bhh2,
                       float* __restrict__ b1p, float* __restrict__ b2p) {
  int p = blockIdx.x * blockDim.x + threadIdx.x;
  if (p < 4096) {
    int bh = p >> 6, g = (p >> 4) & 3, h = p & 15;
    int wrow = g * HID + bh * 16 + h;
    b1p[p] = bih1[wrow] + bhh1[wrow];
    b2p[p] = bih2[wrow] + bhh2[wrow];
  }
}

// ---------------- main persistent kernel ----------------
// bid -> m = (bid&7)>>1 (64-row tile, XCD pair), bh = (bid>>3)|((bid&1)<<5).
// 8 waves: GEMM1 wave w = (r4=w&3 rows 16r4..+15, k2=w>>2 K-half of 34 chunks).
// GEMM2 wave w = K-chunks [8w, 8w+8) of 64; fold + all-to-all -> wave r owns
// row-tile r for both epilogues.
__global__ __launch_bounds__(NTHR, 1) void k_lstm(
    const unsigned short* __restrict__ BA, const unsigned short* __restrict__ BB,
    const unsigned short* __restrict__ XB,
    unsigned short* __restrict__ H1, unsigned short* __restrict__ H2,
    const float* __restrict__ B1P, const float* __restrict__ B2P,
    const float* __restrict__ W2, float* __restrict__ YACC,
    unsigned* __restrict__ BAR)
{
  __shared__ bf16x8 W1L[34 * 4 * 4 * 16];   // 139264 B: W1 frags [c][kq][g][l15]
  __shared__ f32x4  BUF[4 * 4 * 4 * 16];    //  16384 B: reduce buffer

  const int bid = blockIdx.x;
  const int s = bid & 1;
  const int m = (bid & 7) >> 1;
  const int bh = (bid >> 3) | (s << 5);
  const int leaf = s * 4 + ((bid >> 3) & 3);
  const int tid = threadIdx.x;
  const int lane = tid & 63, wave = tid >> 6;   // 0..7
  const int l15 = lane & 15, kq = lane >> 4;
  const int r4 = wave & 3, k2 = wave >> 2;
  const int grow0 = m * 64 + r4 * 16;           // row-tile this wave touches
  const int arow = grow0 + l15;                 // A-fragment row
  const int hcol = bh * 16 + l15;
  const int colb = bh * 64;

  // ---- one-time init ----
  // W1 -> LDS, flat: i = c*256 + kq*64 + g*16 + l  (17 iters per thread)
  for (int i = tid; i < 34 * 256; i += NTHR) {
    const int c = i >> 8, kqq = (i >> 6) & 3, g = (i >> 4) & 3, l = i & 15;
    W1L[i] = ((const bf16x8*)(BA + (size_t)(colb + g * 16 + l) * KA))[c * 4 + kqq];
  }
  // W2 K-slice -> VGPRs: wave w holds global 32k-chunks [8w, 8w+8)
  bf16x8 w2r[8][4];
#pragma unroll
  for (int g = 0; g < 4; ++g) {
    const bf16x8* src = (const bf16x8*)(BB + (size_t)(colb + g * 16 + l15) * KB);
#pragma unroll
    for (int cc = 0; cc < 8; ++cc) w2r[cc][g] = src[(wave * 8 + cc) * 4 + kq];
  }
  const float ba0 = B1P[colb + l15], ba1 = B1P[colb + 16 + l15],
              ba2 = B1P[colb + 32 + l15], ba3 = B1P[colb + 48 + l15];
  const float bb0 = B2P[colb + l15], bb1 = B2P[colb + 16 + l15],
              bb2 = B2P[colb + 32 + l15], bb3 = B2P[colb + 48 + l15];
  const float w2v = W2[hcol];
  float c1r[4] = {0.f, 0.f, 0.f, 0.f};   // live on waves 0-3 only
  float c2r[4] = {0.f, 0.f, 0.f, 0.f};
  __syncthreads();

  for (int p = 0; p <= TT; ++p) {
    const int cur = p & 1, prv = cur ^ 1;

    // ======== GEMM1: rows 16*r4..+15, K-half k2 (17 of 34 chunks) ========
    if (p < TT) {
      f32x4 acc1[4];
#pragma unroll
      for (int g = 0; g < 4; ++g) acc1[g] = (f32x4){0.f, 0.f, 0.f, 0.f};
      const bf16x8* xf  = (const bf16x8*)XB + ((size_t)p * BAT + arow) * 8;
      const bf16x8* h1f = (const bf16x8*)(H1 + (size_t)prv * SZH) + (size_t)arow * 128;
      const int cbeg = k2 * 17;
#pragma unroll
      for (int ci = 0; ci < 17; ++ci) {
        const int c = cbeg + ci;
        bf16x8 a = (c < 2) ? xf[c * 4 + kq] : h1f[(c - 2) * 4 + kq];
#pragma unroll
        for (int g = 0; g < 4; ++g)
          acc1[g] = mfma16(a, W1L[((c * 4 + kq) * 4 + g) * 16 + l15], acc1[g]);
      }
      // K-half reduce: k2=1 publishes, k2=0 folds + epilogue1
      if (k2 == 1) {
#pragma unroll
        for (int g = 0; g < 4; ++g)
          BUF[((r4 * 4 + g) * 4 + kq) * 16 + l15] = acc1[g];
      }
      __syncthreads();
      if (k2 == 0) {
#pragma unroll
        for (int g = 0; g < 4; ++g)
          acc1[g] += BUF[((r4 * 4 + g) * 4 + kq) * 16 + l15];
        unsigned short* h1w = H1 + (size_t)cur * SZH;
#pragma unroll
        for (int j = 0; j < 4; ++j) {
          float gi = acc1[0][j] + ba0, gf = acc1[1][j] + ba1,
                gg = acc1[2][j] + ba2, go = acc1[3][j] + ba3;
          float cn = sigm_(gf) * c1r[j] + sigm_(gi) * tanh_(gg);
          float hn = sigm_(go) * tanh_(cn);
          c1r[j] = cn;
          h1w[(size_t)(grow0 + kq * 4 + j) * HID + hcol] = f2bf(hn);
        }
      }
      __syncthreads();   // BUF reuse by GEMM2 reduce
    }

    // ======== GEMM2: K-split 8-way, full 64x64 partial per wave ========
    if (p >= 1) {
      f32x4 acc2[4][4];   // [row-tile][gate]
#pragma unroll
      for (int i = 0; i < 4; ++i)
#pragma unroll
        for (int g = 0; g < 4; ++g) acc2[i][g] = (f32x4){0.f, 0.f, 0.f, 0.f};
      const bf16x8* af = (wave < 4) ? (const bf16x8*)(H1 + (size_t)prv * SZH)
                                    : (const bf16x8*)(H2 + (size_t)cur * SZH);
      const int fo = (wave < 4 ? wave : wave - 4) * 32;   // frag offset of K-slice
#pragma unroll
      for (int cc = 0; cc < 8; ++cc) {
        bf16x8 afr[4];
#pragma unroll
        for (int i = 0; i < 4; ++i)
          afr[i] = af[(size_t)(m * 64 + i * 16 + l15) * 128 + fo + cc * 4 + kq];
#pragma unroll
        for (int i = 0; i < 4; ++i)
#pragma unroll
          for (int g = 0; g < 4; ++g) acc2[i][g] = mfma16(afr[i], w2r[cc][g], acc2[i][g]);
      }

      // stage A: fold waves 4-7 into 0-3, tile by tile (BUF = 16KB)
#pragma unroll
      for (int t = 0; t < 4; ++t) {
        if (wave >= 4) {
#pragma unroll
          for (int g = 0; g < 4; ++g)
            BUF[(((wave - 4) * 4 + g) * 4 + kq) * 16 + l15] = acc2[t][g];
        }
        __syncthreads();
        if (wave < 4) {
#pragma unroll
          for (int g = 0; g < 4; ++g)
            acc2[t][g] += BUF[((wave * 4 + g) * 4 + kq) * 16 + l15];
        }
        __syncthreads();
      }

      // stage B: balanced all-to-all among waves 0-3 (wave t ends owning tile t)
#pragma unroll
      for (int d = 1; d < 4; ++d) {
#pragma unroll
        for (int t = 0; t < 4; ++t) {
          if (wave < 4 && ((wave + d) & 3) == t) {
#pragma unroll
            for (int g = 0; g < 4; ++g)
              BUF[((wave * 4 + g) * 4 + kq) * 16 + l15] = acc2[t][g];
          }
        }
        __syncthreads();
#pragma unroll
        for (int t = 0; t < 4; ++t) {
          if (wave == t) {
            const int rs = (t - d) & 3;
#pragma unroll
            for (int g = 0; g < 4; ++g)
              acc2[t][g] += BUF[((rs * 4 + g) * 4 + kq) * 16 + l15];
          }
        }
        if (d < 3) __syncthreads();
      }

      // epilogue 2 on waves 0-3 (static extraction)
      if (wave < 4) {
        unsigned short* h2w = H2 + (size_t)prv * SZH;   // h2(p-1) -> buffer (p-1)&1
        f32x4 g0, g1, g2, g3;
#pragma unroll
        for (int t = 0; t < 4; ++t)
          if (wave == t) { g0 = acc2[t][0]; g1 = acc2[t][1]; g2 = acc2[t][2]; g3 = acc2[t][3]; }
#pragma unroll
        for (int j = 0; j < 4; ++j) {
          float gi = g0[j] + bb0, gf = g1[j] + bb1, gg = g2[j] + bb2, go = g3[j] + bb3;
          float cn = sigm_(gf) * c2r[j] + sigm_(gi) * tanh_(gg);
          float hn = sigm_(go) * tanh_(cn);
          c2r[j] = cn;
          int gr = grow0 + kq * 4 + j;
          h2w[(size_t)gr * HID + hcol] = f2bf(hn);
          float v = hn * w2v;
          v += __shfl_xor(v, 1);
          v += __shfl_xor(v, 2);
          v += __shfl_xor(v, 4);
          v += __shfl_xor(v, 8);
          if (l15 == 0) atomicAdd(YACC + ((size_t)(p - 1) * BAT + gr) * 8 + ((bid >> 3) & 7), v);
        }
      }
    }

    if (p < TT) group_barrier(BAR, (unsigned)(p + 1), m, leaf);
  }
}

__global__ void k_fin(const float* __restrict__ yacc, const float* __restrict__ b2,
                      float* __restrict__ out) {
  int i = blockIdx.x * blockDim.x + threadIdx.x;
  if (i < TT * BAT) {
    const float* y = yacc + (size_t)i * 8;
    float a = (y[0] + y[1]) + (y[2] + y[3]) + ((y[4] + y[5]) + (y[6] + y[7]));
    out[i] = 1.0f / (1.0f + __expf(-(a + b2[0])));
  }
}

// ---------------------------------------------------------------------------
extern "C" void kernel_launch(void* const* d_in, const int* in_sizes, int n_in,
                              void* d_out, int out_size, void* d_ws, size_t ws_size,
                              hipStream_t stream) {
  const float* x    = (const float*)d_in[0];
  const float* Wih1 = (const float*)d_in[1];
  const float* Whh1 = (const float*)d_in[2];
  const float* bih1 = (const float*)d_in[3];
  const float* bhh1 = (const float*)d_in[4];
  const float* Wih2 = (const float*)d_in[5];
  const float* Whh2 = (const float*)d_in[6];
  const float* bih2 = (const float*)d_in[7];
  const float* bhh2 = (const float*)d_in[8];
  const float* W2   = (const float*)d_in[9];
  const float* b2   = (const float*)d_in[10];
  (void)in_sizes; (void)n_in; (void)out_size; (void)ws_size;

  char* ws = (char*)d_ws;
  unsigned short* BA  = (unsigned short*)(ws + OFF_BA);
  unsigned short* BBp = (unsigned short*)(ws + OFF_BB);
  unsigned short* XBp = (unsigned short*)(ws + OFF_XB);
  unsigned short* H1  = (unsigned short*)(ws + OFF_H1);
  unsigned short* H2  = (unsigned short*)(ws + OFF_H2);
  float* YACC = (float*)(ws + OFF_Y);
  float* B1P  = (float*)(ws + OFF_B1P);
  float* B2P  = (float*)(ws + OFF_B2P);
  unsigned* BAR = (unsigned*)(ws + OFF_BAR);

  k_zero<<<512, 256, 0, stream>>>((unsigned*)(ws + OFF_H1), (long)((WS_END - OFF_H1) / 4));
  k_packw<<<1024, 256, 0, stream>>>(Wih1, Whh1, BA, INP, KA);
  k_packw<<<2048, 256, 0, stream>>>(Wih2, Whh2, BBp, HID, KB);
  k_convx<<<1024, 256, 0, stream>>>(x, XBp);
  k_bias<<<16, 256, 0, stream>>>(bih1, bhh1, bih2, bhh2, B1P, B2P);
  k_lstm<<<NBLK, NTHR, 0, stream>>>(BA, BBp, XBp, H1, H2, B1P, B2P, W2, YACC, BAR);
  k_fin<<<512, 256, 0, stream>>>(YACC, b2, (float*)d_out);
}